// Round 19
// baseline (528.364 us; speedup 1.0000x reference)
//
#include <hip/hip_runtime.h>
#include <hip/hip_bf16.h>

// GIN forward: N=10000 nodes, E=80000 edges, per-node feature block [A=2][C=15][D=64]
// All inter-kernel tensors stored bf16; all reductions/BN/pool math in fp32.
// SLICE-MAJOR layout: row r = ac*10000 + n (ac=0..29). BN channel = idx%64 (unchanged).
// LESSONS LEDGER:
//  - R3/R11: do NOT fuse gather with GEMM (W-prologue can't amortize over 30 rows/node).
//  - R13/R15: cooperative BCD fusion refuted: grid.sync() ~65us each on 8-XCD MI355X.
//  - R16: slice-major gather (per-slice 1.28MB, XCD-partitioned) -> L2-resident. WIN.
//  - R17: 2-tile ILP unroll refuted (VGPR 60->88 dropped occupancy, offsetting MLP).
//  - R18: fold (1+eps)*x into gather -> passA single-stream pure-load A-frag. WIN.
//  - R19: pre-transposed bf16 weights (k_wprep) -> 8x16B pure-load W-frags; grid 1024->2048.
#define N_NODES   10000
#define N_EDGES   80000
#define R_TOTAL   300000
#define ELEMS     19200000   // R_TOTAL*64
#define NODE_F    1920       // 30*64 elements per node
#define N_TILES   18750      // R_TOTAL/16
#define GEMM_GRID 2048       // passA/passB grid (cheap prologue now amortizes at 2.3 tiles/wave)
#define BPS       313        // gather blocks per slice (32 nodes/block)
#define PD_X      40         // passD blocks per slice (250 nodes each)

typedef __attribute__((ext_vector_type(8))) short short8;   // 8 bf16
typedef __attribute__((ext_vector_type(4))) float f32x4;
typedef __attribute__((ext_vector_type(4))) unsigned int u32x4;
typedef __attribute__((ext_vector_type(2))) unsigned int u32x2;
typedef unsigned short ushort_t;

__device__ __forceinline__ unsigned short f2bf(float f) {
    unsigned u = __builtin_bit_cast(unsigned, f);
    unsigned r = u + 0x7fff + ((u >> 16) & 1);   // RNE
    return (unsigned short)(r >> 16);
}
__device__ __forceinline__ float lo_f(unsigned u) { return __builtin_bit_cast(float, u << 16); }
__device__ __forceinline__ float hi_f(unsigned u) { return __builtin_bit_cast(float, u & 0xffff0000u); }
__device__ __forceinline__ unsigned packbf(float lo, float hi) {
    return ((unsigned)f2bf(hi) << 16) | (unsigned)f2bf(lo);
}

// inline BatchNorm coefficient computation (channel = d in 0..63)
__device__ __forceinline__ void bn_coef(const float* __restrict__ ssum,
                                        const float* __restrict__ ssq,
                                        const float* __restrict__ g,
                                        const float* __restrict__ b, int j,
                                        float& sc, float& sh) {
    const float invM = 1.0f / (float)R_TOTAL;
    float m = ssum[j] * invM;
    float v = ssq[j] * invM - m * m;
    sc = g[j] * rsqrtf(v + 1e-5f);
    sh = b[j] - m * sc;
}

// ---------------- wprep: Wt[mat][col][k] = bf16(W[mat][k][col]), mat = {W0l0,W1l0,W0l1,W1l1} ----------------
__global__ __launch_bounds__(256) void k_wprep(const float* __restrict__ W0,
                                               const float* __restrict__ W1,
                                               ushort_t* __restrict__ wt) {
    int idx = blockIdx.x * 256 + threadIdx.x;      // 64 blocks -> 16384 = 4*4096
    int mm = idx >> 12, r = idx & 4095;
    int kk = r >> 6, col = r & 63;                 // read contiguous over col
    int l = mm >> 1;
    const float* src = ((mm & 1) ? W1 : W0) + l * 4096;
    wt[mm * 4096 + col * 64 + kk] = f2bf(src[kk * 64 + col]);
}

// ---------------- transpose h[a][d][c][n] -> xb[ac][n][d] (bf16, slice-major), + pooled0 ----------------
__global__ __launch_bounds__(256) void k_transpose(const float* __restrict__ h,
                                                   ushort_t* __restrict__ xb,
                                                   float* __restrict__ pooled) {
    __shared__ float tile[64][65];    // [d][nn]
    int tn = blockIdx.x;              // n-tile 0..156
    int ac = blockIdx.y;              // 0..29
    int a = ac / 15, c = ac % 15;
    int t = threadIdx.x;
    int n0 = tn * 64;

    int r = t >> 4, g = t & 15;
    int nbase = n0 + 4 * g;
    const float* hp = h + (size_t)a * 9600000 + (size_t)c * 10000;
#pragma unroll
    for (int it = 0; it < 4; it++) {
        int d = it * 16 + r;
        const float* p = hp + (size_t)d * 150000 + nbase;
        float4 v;
        if (nbase + 3 < N_NODES) {
            v = *(const float4*)p;
        } else {
            v.x = (nbase + 0 < N_NODES) ? p[0] : 0.f;
            v.y = (nbase + 1 < N_NODES) ? p[1] : 0.f;
            v.z = (nbase + 2 < N_NODES) ? p[2] : 0.f;
            v.w = (nbase + 3 < N_NODES) ? p[3] : 0.f;
        }
        tile[d][4 * g + 0] = v.x;
        tile[d][4 * g + 1] = v.y;
        tile[d][4 * g + 2] = v.z;
        tile[d][4 * g + 3] = v.w;
    }
    __syncthreads();

    int nn = t >> 2, dg = (t & 3) * 16;
    int n = n0 + nn;
    if (n < N_NODES) {
        u32x4 oA, oB;
#pragma unroll
        for (int q = 0; q < 4; q++) {
            oA[q] = packbf(tile[dg + 2 * q][nn],     tile[dg + 2 * q + 1][nn]);
            oB[q] = packbf(tile[dg + 8 + 2 * q][nn], tile[dg + 8 + 2 * q + 1][nn]);
        }
        ushort_t* dst = xb + ((size_t)ac * N_NODES + n) * 64 + dg;   // slice-major
        *(u32x4*)dst = oA;
        *(u32x4*)(dst + 8) = oB;
    }

    if (t < 64) {
        float s = 0.f;
        int lim = min(64, N_NODES - n0);
        for (int j = 0; j < lim; j++) s += tile[t][j];
        atomicAdd(&pooled[ac * 64 + t], s);
    }
}

// ---------------- CSR build: degree -> scan -> fill ----------------
__global__ void k_deg(const int* __restrict__ dst, int* __restrict__ deg) {
    int e = blockIdx.x * 256 + threadIdx.x;
    if (e < N_EDGES) atomicAdd(&deg[dst[e]], 1);
}

__global__ __launch_bounds__(256) void k_scan(const int* __restrict__ deg,
                                              int* __restrict__ off,
                                              int* __restrict__ cursor) {
    __shared__ int buf[256];
    int t = threadIdx.x;
    int c0 = t * 40;                 // 256*40 = 10240 >= 10000
    int local[40];
    int s = 0;
    for (int i = 0; i < 40; i++) {
        int idx = c0 + i;
        int d = (idx < N_NODES) ? deg[idx] : 0;
        local[i] = d;
        s += d;
    }
    buf[t] = s;
    __syncthreads();
    for (int st = 1; st < 256; st <<= 1) {
        int v = (t >= st) ? buf[t - st] : 0;
        __syncthreads();
        buf[t] += v;
        __syncthreads();
    }
    int run = buf[t] - s;
    for (int i = 0; i < 40; i++) {
        int idx = c0 + i;
        if (idx < N_NODES) {
            off[idx] = run;
            cursor[idx] = run;
            run += local[i];
        }
    }
    if (t == 255) off[N_NODES] = buf[255];
}

__global__ void k_fill(const int* __restrict__ src, const int* __restrict__ dst,
                       int* __restrict__ cursor, int* __restrict__ csr) {
    int e = blockIdx.x * 256 + threadIdx.x;
    if (e < N_EDGES) {
        int p = atomicAdd(&cursor[dst[e]], 1);
        csr[p] = src[e];
    }
}

// ---------------- gather (slice-major, XCD-partitioned), emits z = (1+eps)*x[n] + sum x[src] ----------------
__global__ __launch_bounds__(256) void k_gather(const ushort_t* __restrict__ xs,
                                                ushort_t* __restrict__ zs,
                                                const int* __restrict__ off,
                                                const int* __restrict__ csr,
                                                const float* __restrict__ epsp, int l) {
    int bid = blockIdx.x;
    int xcd = bid & 7, k = bid >> 3;
    int base = (xcd < 6) ? xcd * 4 : 24 + (xcd - 6) * 3;   // slices per XCD: 4,4,4,4,4,4,3,3
    int nsl  = (xcd < 6) ? 4 : 3;
    int si = k / BPS;
    if (si >= nsl) return;
    int ac = base + si;
    int ng = k - si * BPS;
    int t = threadIdx.x;
    int nl = t >> 3, c8 = t & 7;       // 32 nodes/block, 8 threads/node (16B chunk each)
    int n = ng * 32 + nl;
    if (n >= N_NODES) return;

    const ushort_t* xsl = xs + (size_t)ac * N_NODES * 64;
    float e1 = 1.0f + epsp[l];
    float acc[8];
    {
        u32x4 xv = *(const u32x4*)(xsl + (size_t)n * 64 + c8 * 8);
#pragma unroll
        for (int q = 0; q < 4; q++) {
            acc[2 * q]     = e1 * lo_f(xv[q]);
            acc[2 * q + 1] = e1 * hi_f(xv[q]);
        }
    }
    int e0 = off[n], e1i = off[n + 1];
    int i = e0;
    for (; i + 4 <= e1i; i += 4) {
        int s0 = csr[i], s1 = csr[i + 1], s2 = csr[i + 2], s3 = csr[i + 3];
        u32x4 v0 = *(const u32x4*)(xsl + (size_t)s0 * 64 + c8 * 8);
        u32x4 v1 = *(const u32x4*)(xsl + (size_t)s1 * 64 + c8 * 8);
        u32x4 v2 = *(const u32x4*)(xsl + (size_t)s2 * 64 + c8 * 8);
        u32x4 v3 = *(const u32x4*)(xsl + (size_t)s3 * 64 + c8 * 8);
#pragma unroll
        for (int q = 0; q < 4; q++) {
            acc[2 * q]     += (lo_f(v0[q]) + lo_f(v1[q])) + (lo_f(v2[q]) + lo_f(v3[q]));
            acc[2 * q + 1] += (hi_f(v0[q]) + hi_f(v1[q])) + (hi_f(v2[q]) + hi_f(v3[q]));
        }
    }
    for (; i < e1i; i++) {
        int s0 = csr[i];
        u32x4 v = *(const u32x4*)(xsl + (size_t)s0 * 64 + c8 * 8);
#pragma unroll
        for (int q = 0; q < 4; q++) {
            acc[2 * q]     += lo_f(v[q]);
            acc[2 * q + 1] += hi_f(v[q]);
        }
    }
    u32x4 o;
#pragma unroll
    for (int q = 0; q < 4; q++) o[q] = packbf(acc[2 * q], acc[2 * q + 1]);
    *(u32x4*)(zs + ((size_t)ac * N_NODES + n) * 64 + c8 * 8) = o;
}

// ---------------- passA (MFMA): to = z @ W0 + b0 ; stats(to). Pure-load A and W frags ----------------
__global__ __launch_bounds__(256) void k_passA(const ushort_t* __restrict__ zb,
                                               ushort_t* __restrict__ to,
                                               const ushort_t* __restrict__ wt,  // [col][k] bf16
                                               const float* __restrict__ bias,
                                               float* __restrict__ ssum, float* __restrict__ ssq) {
    int tid = threadIdx.x;
    int lane = tid & 63, wid = tid >> 6;
    int m = lane & 15, kg = lane >> 4;

    short8 bfr[2][4];                 // [kstep][nt] ; col = 4m+nt; pure 16B loads
#pragma unroll
    for (int s = 0; s < 2; s++)
#pragma unroll
        for (int nt = 0; nt < 4; nt++)
            bfr[s][nt] = *(const short8*)(wt + (4 * m + nt) * 64 + s * 32 + kg * 8);
    float bcol[4];
#pragma unroll
    for (int nt = 0; nt < 4; nt++) bcol[nt] = bias[4 * m + nt];

    float s0a[4] = {0.f, 0.f, 0.f, 0.f}, s1a[4] = {0.f, 0.f, 0.f, 0.f};

    for (int tile = blockIdx.x * 4 + wid; tile < N_TILES; tile += gridDim.x * 4) {
        size_t row0 = (size_t)tile * 16;
        const short8* zr = (const short8*)(zb + (row0 + m) * 64);
        short8 afr0 = zr[kg];          // k = kg*8 .. +7
        short8 afr1 = zr[4 + kg];      // k = 32 + kg*8 .. +7
        f32x4 acc0 = {0,0,0,0}, acc1 = {0,0,0,0}, acc2 = {0,0,0,0}, acc3 = {0,0,0,0};
        acc0 = __builtin_amdgcn_mfma_f32_16x16x32_bf16(afr0, bfr[0][0], acc0, 0, 0, 0);
        acc1 = __builtin_amdgcn_mfma_f32_16x16x32_bf16(afr0, bfr[0][1], acc1, 0, 0, 0);
        acc2 = __builtin_amdgcn_mfma_f32_16x16x32_bf16(afr0, bfr[0][2], acc2, 0, 0, 0);
        acc3 = __builtin_amdgcn_mfma_f32_16x16x32_bf16(afr0, bfr[0][3], acc3, 0, 0, 0);
        acc0 = __builtin_amdgcn_mfma_f32_16x16x32_bf16(afr1, bfr[1][0], acc0, 0, 0, 0);
        acc1 = __builtin_amdgcn_mfma_f32_16x16x32_bf16(afr1, bfr[1][1], acc1, 0, 0, 0);
        acc2 = __builtin_amdgcn_mfma_f32_16x16x32_bf16(afr1, bfr[1][2], acc2, 0, 0, 0);
        acc3 = __builtin_amdgcn_mfma_f32_16x16x32_bf16(afr1, bfr[1][3], acc3, 0, 0, 0);
        ushort_t* tw = to + (row0 + kg * 4) * 64 + 4 * m;
#pragma unroll
        for (int r = 0; r < 4; r++) {
            float v0 = acc0[r] + bcol[0];
            float v1 = acc1[r] + bcol[1];
            float v2 = acc2[r] + bcol[2];
            float v3 = acc3[r] + bcol[3];
            u32x2 pk;
            pk[0] = packbf(v0, v1);
            pk[1] = packbf(v2, v3);
            *(u32x2*)(tw + (size_t)r * 64) = pk;
            s0a[0] += v0; s1a[0] += v0 * v0;
            s0a[1] += v1; s1a[1] += v1 * v1;
            s0a[2] += v2; s1a[2] += v2 * v2;
            s0a[3] += v3; s1a[3] += v3 * v3;
        }
    }
    __shared__ float shs0[64], shs1[64];
    if (tid < 64) { shs0[tid] = 0.f; shs1[tid] = 0.f; }
    __syncthreads();
#pragma unroll
    for (int nt = 0; nt < 4; nt++) {
        atomicAdd(&shs0[4 * m + nt], s0a[nt]);
        atomicAdd(&shs1[4 * m + nt], s1a[nt]);
    }
    __syncthreads();
    if (tid < 64) {
        atomicAdd(&ssum[tid], shs0[tid]);
        atomicAdd(&ssq[tid], shs1[tid]);
    }
}

// ---------------- passB (MFMA): to = relu(bn0(ti)) @ W1 + b1 ; stats(to) ----------------
__global__ __launch_bounds__(256) void k_passB(const ushort_t* __restrict__ ti,
                                               ushort_t* __restrict__ to,
                                               const ushort_t* __restrict__ wt,  // [col][k] bf16
                                               const float* __restrict__ bias,
                                               const float* __restrict__ ssum0,
                                               const float* __restrict__ ssq0,
                                               const float* __restrict__ g0,
                                               const float* __restrict__ be0,
                                               float* __restrict__ ssum, float* __restrict__ ssq) {
    int tid = threadIdx.x;
    int lane = tid & 63, wid = tid >> 6;
    int m = lane & 15, kg = lane >> 4;

    short8 bfr[2][4];                 // col = 4m+nt; pure 16B loads
#pragma unroll
    for (int s = 0; s < 2; s++)
#pragma unroll
        for (int nt = 0; nt < 4; nt++)
            bfr[s][nt] = *(const short8*)(wt + (4 * m + nt) * 64 + s * 32 + kg * 8);
    float bcol[4];
#pragma unroll
    for (int nt = 0; nt < 4; nt++) bcol[nt] = bias[4 * m + nt];
    float scv[2][8], shv[2][8];       // BN for input channels k = s*32+kg*8+j
#pragma unroll
    for (int s = 0; s < 2; s++)
#pragma unroll
        for (int j = 0; j < 8; j++)
            bn_coef(ssum0, ssq0, g0, be0, s * 32 + kg * 8 + j, scv[s][j], shv[s][j]);

    float s0a[4] = {0.f, 0.f, 0.f, 0.f}, s1a[4] = {0.f, 0.f, 0.f, 0.f};

    for (int tile = blockIdx.x * 4 + wid; tile < N_TILES; tile += gridDim.x * 4) {
        size_t row0 = (size_t)tile * 16;
        const u32x4* tr = (const u32x4*)(ti + (row0 + m) * 64);
        short8 afr[2];
#pragma unroll
        for (int s = 0; s < 2; s++) {
            u32x4 tv = tr[s * 4 + kg];
            u32x4 zv;
#pragma unroll
            for (int q = 0; q < 4; q++) {
                float zl_ = fmaxf(fmaf(lo_f(tv[q]), scv[s][2 * q],     shv[s][2 * q]),     0.f);
                float zh_ = fmaxf(fmaf(hi_f(tv[q]), scv[s][2 * q + 1], shv[s][2 * q + 1]), 0.f);
                zv[q] = packbf(zl_, zh_);
            }
            afr[s] = __builtin_bit_cast(short8, zv);
        }
        f32x4 acc0 = {0,0,0,0}, acc1 = {0,0,0,0}, acc2 = {0,0,0,0}, acc3 = {0,0,0,0};
#pragma unroll
        for (int s = 0; s < 2; s++) {
            acc0 = __builtin_amdgcn_mfma_f32_16x16x32_bf16(afr[s], bfr[s][0], acc0, 0, 0, 0);
            acc1 = __builtin_amdgcn_mfma_f32_16x16x32_bf16(afr[s], bfr[s][1], acc1, 0, 0, 0);
            acc2 = __builtin_amdgcn_mfma_f32_16x16x32_bf16(afr[s], bfr[s][2], acc2, 0, 0, 0);
            acc3 = __builtin_amdgcn_mfma_f32_16x16x32_bf16(afr[s], bfr[s][3], acc3, 0, 0, 0);
        }
        ushort_t* tw = to + (row0 + kg * 4) * 64 + 4 * m;
#pragma unroll
        for (int r = 0; r < 4; r++) {
            float v0 = acc0[r] + bcol[0];
            float v1 = acc1[r] + bcol[1];
            float v2 = acc2[r] + bcol[2];
            float v3 = acc3[r] + bcol[3];
            u32x2 pk;
            pk[0] = packbf(v0, v1);
            pk[1] = packbf(v2, v3);
            *(u32x2*)(tw + (size_t)r * 64) = pk;
            s0a[0] += v0; s1a[0] += v0 * v0;
            s0a[1] += v1; s1a[1] += v1 * v1;
            s0a[2] += v2; s1a[2] += v2 * v2;
            s0a[3] += v3; s1a[3] += v3 * v3;
        }
    }
    __shared__ float shs0[64], shs1[64];
    if (tid < 64) { shs0[tid] = 0.f; shs1[tid] = 0.f; }
    __syncthreads();
#pragma unroll
    for (int nt = 0; nt < 4; nt++) {
        atomicAdd(&shs0[4 * m + nt], s0a[nt]);
        atomicAdd(&shs1[4 * m + nt], s1a[nt]);
    }
    __syncthreads();
    if (tid < 64) {
        atomicAdd(&ssum[tid], shs0[tid]);
        atomicAdd(&ssq[tid], shs1[tid]);
    }
}

// ---------------- statsC: stats of u = relu(bn_a(t3)), read-only bf16 ----------------
__global__ __launch_bounds__(256) void k_statsC(const ushort_t* __restrict__ tb,
                                                const float* __restrict__ ssum1,
                                                const float* __restrict__ ssq1,
                                                const float* __restrict__ ga,
                                                const float* __restrict__ ba,
                                                float* __restrict__ ssum2,
                                                float* __restrict__ ssq2) {
    __shared__ float shs0[64], shs1[64];
    int tid = threadIdx.x;
    if (tid < 64) { shs0[tid] = 0.f; shs1[tid] = 0.f; }
    __syncthreads();
    int ch0 = (tid & 7) * 8;          // chunk-in-row = tid%8 (stride is multiple of 8)
    float sc[8], sh[8];
#pragma unroll
    for (int j = 0; j < 8; j++) bn_coef(ssum1, ssq1, ga, ba, ch0 + j, sc[j], sh[j]);
    float s0[8] = {0,0,0,0,0,0,0,0}, s1[8] = {0,0,0,0,0,0,0,0};
    const u32x4* t4 = (const u32x4*)tb;
    const int total = ELEMS / 8;
    int stride = gridDim.x * 256;
    for (int i = blockIdx.x * 256 + tid; i < total; i += stride) {
        u32x4 v = t4[i];
#pragma unroll
        for (int q = 0; q < 4; q++) {
            float e;
            e = fmaxf(fmaf(lo_f(v[q]), sc[2 * q],     sh[2 * q]),     0.f);
            s0[2 * q] += e;     s1[2 * q] += e * e;
            e = fmaxf(fmaf(hi_f(v[q]), sc[2 * q + 1], sh[2 * q + 1]), 0.f);
            s0[2 * q + 1] += e; s1[2 * q + 1] += e * e;
        }
    }
#pragma unroll
    for (int j = 0; j < 8; j++) {
        atomicAdd(&shs0[ch0 + j], s0[j]);
        atomicAdd(&shs1[ch0 + j], s1[j]);
    }
    __syncthreads();
    if (tid < 64) {
        atomicAdd(&ssum2[tid], shs0[tid]);
        atomicAdd(&ssq2[tid], shs1[tid]);
    }
}

// ---------------- passD (slice-major): grid (PD_X, 30) ----------------
__global__ __launch_bounds__(256) void k_passD(const ushort_t* __restrict__ tb,
                                               ushort_t* __restrict__ xb,
                                               const float* __restrict__ ssum1,
                                               const float* __restrict__ ssq1,
                                               const float* __restrict__ ga,
                                               const float* __restrict__ ba,
                                               const float* __restrict__ ssum2,
                                               const float* __restrict__ ssq2,
                                               const float* __restrict__ go,
                                               const float* __restrict__ bo,
                                               float* __restrict__ pp,   // [30*PD_X][64]
                                               int writeX) {
    __shared__ float pl[64];
    int t = threadIdx.x;
    int nl = t >> 3, c8 = t & 7;
    int ac = blockIdx.y, bx = blockIdx.x;
    int ch0 = c8 * 8;                 // BN channel base (d only)
    float sc1[8], sh1[8], sc2[8], sh2[8];
#pragma unroll
    for (int j = 0; j < 8; j++) {
        bn_coef(ssum1, ssq1, ga, ba, ch0 + j, sc1[j], sh1[j]);
        bn_coef(ssum2, ssq2, go, bo, ch0 + j, sc2[j], sh2[j]);
    }
    if (t < 64) pl[t] = 0.f;
    __syncthreads();

    float pool[8] = {0,0,0,0,0,0,0,0};
    int n0 = bx * 250;
    for (int n = n0 + nl; n < n0 + 250; n += 32) {
        size_t r = (size_t)ac * N_NODES + n;
        u32x4 v = *(const u32x4*)(tb + r * 64 + ch0);
        u32x4 o;
#pragma unroll
        for (int q = 0; q < 4; q++) {
            float el = fmaxf(fmaf(fmaxf(fmaf(lo_f(v[q]), sc1[2 * q], sh1[2 * q]), 0.f),
                                  sc2[2 * q], sh2[2 * q]), 0.f);
            float eh = fmaxf(fmaf(fmaxf(fmaf(hi_f(v[q]), sc1[2 * q + 1], sh1[2 * q + 1]), 0.f),
                                  sc2[2 * q + 1], sh2[2 * q + 1]), 0.f);
            pool[2 * q] += el;
            pool[2 * q + 1] += eh;
            o[q] = packbf(el, eh);
        }
        if (writeX) *(u32x4*)(xb + r * 64 + ch0) = o;
    }
#pragma unroll
    for (int j = 0; j < 8; j++) atomicAdd(&pl[ch0 + j], pool[j]);
    __syncthreads();
    if (t < 64) pp[((size_t)ac * PD_X + bx) * 64 + t] = pl[t];
}

// ---------------- redpool: pooled[(z+1)][ch] = sum over PD_X partials; grid (8,1,2) ----------------
__global__ __launch_bounds__(256) void k_redpool(const float* __restrict__ pp0,
                                                 const float* __restrict__ pp1,
                                                 float* __restrict__ pooled) {
    int ch = blockIdx.x * 256 + threadIdx.x;
    if (ch >= NODE_F) return;
    const float* pp = (blockIdx.z == 0) ? pp0 : pp1;
    int ac = ch >> 6, d = ch & 63;
    float a = 0.f;
    for (int b = 0; b < PD_X; b++) a += pp[((size_t)ac * PD_X + b) * 64 + d];
    pooled[(blockIdx.z + 1) * NODE_F + ch] = a;
}

// ---------------- final readout: score + fc -> out[2] ----------------
__global__ void k_final(const float* __restrict__ pooled,   // [3][1920]
                        const float* __restrict__ Wp,       // [3][64][10]
                        const float* __restrict__ bp,       // [3][10]
                        const float* __restrict__ Wfc,      // [15][10]
                        const float* __restrict__ bfc, float* __restrict__ out) {
    __shared__ float oa[2];
    int t = threadIdx.x;
    if (t < 2) oa[t] = 0.f;
    __syncthreads();
    if (t < 300) {
        int a = t / 150, rem = t % 150, c = rem / 10, hh = rem % 10;
        int ac = a * 15 + c;
        float sc_sum = 0.f;
        for (int i = 0; i < 3; i++) {
            float s = bp[i * 10 + hh];
            const float* pp = pooled + i * NODE_F + ac * 64;
            const float* wp = Wp + i * 640 + hh;
            for (int d = 0; d < 64; d++) s += pp[d] * wp[d * 10];
            sc_sum += s;
        }
        atomicAdd(&oa[a], sc_sum * Wfc[c * 10 + hh]);
    }
    __syncthreads();
    if (t < 2) out[t] = oa[t] + bfc[0];
}

extern "C" void kernel_launch(void* const* d_in, const int* in_sizes, int n_in,
                              void* d_out, int out_size, void* d_ws, size_t ws_size,
                              hipStream_t stream) {
    const float* h   = (const float*)d_in[0];
    const float* eps = (const float*)d_in[1];
    const float* W0  = (const float*)d_in[2];
    const float* b0  = (const float*)d_in[3];
    const float* g0  = (const float*)d_in[4];
    const float* be0 = (const float*)d_in[5];
    const float* W1  = (const float*)d_in[6];
    const float* b1  = (const float*)d_in[7];
    const float* ga  = (const float*)d_in[8];
    const float* ba  = (const float*)d_in[9];
    const float* go  = (const float*)d_in[10];
    const float* bo  = (const float*)d_in[11];
    const float* Wp  = (const float*)d_in[12];
    const float* bp  = (const float*)d_in[13];
    const float* Wfc = (const float*)d_in[14];
    const float* bfc = (const float*)d_in[15];
    const int*   src = (const int*)d_in[16];
    const int*   dst = (const int*)d_in[17];
    float* out = (float*)d_out;

    ushort_t* xb   = (ushort_t*)d_ws;            // [ELEMS] bf16 (node features, slice-major)
    ushort_t* bufP = xb + ELEMS;                 // [ELEMS] bf16 (z / t3)
    ushort_t* bufQ = bufP + ELEMS;               // [ELEMS] bf16 (t1)
    float* small   = (float*)(bufQ + ELEMS);
    float* bn = small;                           // 6 x [sum64|sq64] padded to 256
    float* pooled = small + 6 * 256;             // [3][1920]
    int* ideg = (int*)(pooled + 3 * NODE_F);     // [10000]
    int* ioff = ideg + N_NODES;                  // [10001]
    int* icur = ioff + N_NODES + 1;              // [10000]
    int* icsr = icur + N_NODES;                  // [80000]
    float* pp0 = (float*)(icsr + N_EDGES);       // [30*PD_X][64] layer-1 pool partials
    float* pp1 = pp0 + 30 * PD_X * 64;           // [30*PD_X][64] layer-2 pool partials
    ushort_t* wt = (ushort_t*)(pp1 + 30 * PD_X * 64);   // [4][64][64] bf16 transposed weights

    hipMemsetAsync(small, 0,
                   (6 * 256 + 3 * NODE_F) * sizeof(float) + N_NODES * sizeof(int), stream);

    k_wprep<<<64, 256, 0, stream>>>(W0, W1, wt);
    k_deg<<<(N_EDGES + 255) / 256, 256, 0, stream>>>(dst, ideg);
    k_scan<<<1, 256, 0, stream>>>(ideg, ioff, icur);
    k_fill<<<(N_EDGES + 255) / 256, 256, 0, stream>>>(src, dst, icur, icsr);

    k_transpose<<<dim3(157, 30), 256, 0, stream>>>(h, xb, pooled);

    for (int l = 0; l < 2; l++) {
        float* s0s = bn + l * 3 * 256;
        float* s1s = s0s + 256;
        float* s2s = s1s + 256;
        float* ppl = (l == 0) ? pp0 : pp1;
        const ushort_t* wt0 = wt + (l * 2 + 0) * 4096;   // W0 of layer l
        const ushort_t* wt1 = wt + (l * 2 + 1) * 4096;   // W1 of layer l
        k_gather<<<8 * 4 * BPS, 256, 0, stream>>>(xb, bufP, ioff, icsr, eps, l);
        k_passA<<<GEMM_GRID, 256, 0, stream>>>(bufP, bufQ, wt0, b0 + l * 64,
                                               s0s, s0s + 64);
        k_passB<<<GEMM_GRID, 256, 0, stream>>>(bufQ, bufP, wt1, b1 + l * 64,
                                               s0s, s0s + 64, g0 + l * 64, be0 + l * 64,
                                               s1s, s1s + 64);
        k_statsC<<<1024, 256, 0, stream>>>(bufP, s1s, s1s + 64, ga + l * 64, ba + l * 64,
                                           s2s, s2s + 64);
        k_passD<<<dim3(PD_X, 30), 256, 0, stream>>>(bufP, xb, s1s, s1s + 64,
                                                    ga + l * 64, ba + l * 64,
                                                    s2s, s2s + 64, go + l * 64, bo + l * 64,
                                                    ppl, (l == 0) ? 1 : 0);
    }
    k_redpool<<<dim3(8, 1, 2), 256, 0, stream>>>(pp0, pp1, pooled);
    k_final<<<1, 320, 0, stream>>>(pooled, Wp, bp, Wfc, bfc, out);
}

// Round 20
// 432.366 us; speedup vs baseline: 1.2220x; 1.2220x over previous
//
#include <hip/hip_runtime.h>
#include <hip/hip_bf16.h>

// GIN forward: N=10000 nodes, E=80000 edges, per-node feature block [A=2][C=15][D=64]
// All inter-kernel tensors stored bf16; all reductions/BN/pool math in fp32.
// SLICE-MAJOR layout: row r = ac*10000 + n (ac=0..29). BN channel = idx%64 (unchanged).
// LESSONS LEDGER:
//  - R3/R11: do NOT fuse gather with GEMM (W-prologue can't amortize over 30 rows/node).
//  - R13/R15: cooperative BCD fusion refuted: grid.sync() ~65us each on 8-XCD MI355X.
//  - R16: slice-major gather (per-slice 1.28MB, XCD-partitioned) -> L2-resident. WIN.
//  - R17: 2-tile ILP unroll refuted (VGPR 60->88 dropped occupancy, offsetting MLP).
//  - R18: fold (1+eps)*x into gather -> passA single-stream pure-load A-frag. WIN.
//  - R19: GEMM_GRID 2048 refuted (bn_coef prologue = 64 scalar loads/wave; 2.3 tiles/wave
//    can't amortize). Keep wprep, grid stays 1024.
#define N_NODES   10000
#define N_EDGES   80000
#define R_TOTAL   300000
#define ELEMS     19200000   // R_TOTAL*64
#define NODE_F    1920       // 30*64 elements per node
#define N_TILES   18750      // R_TOTAL/16
#define GEMM_GRID 1024       // passA/passB grid: 4.6 tiles/wave amortizes prologues
#define BPS       313        // gather blocks per slice (32 nodes/block)
#define PD_X      40         // passD blocks per slice (250 nodes each)

typedef __attribute__((ext_vector_type(8))) short short8;   // 8 bf16
typedef __attribute__((ext_vector_type(4))) float f32x4;
typedef __attribute__((ext_vector_type(4))) unsigned int u32x4;
typedef __attribute__((ext_vector_type(2))) unsigned int u32x2;
typedef unsigned short ushort_t;

__device__ __forceinline__ unsigned short f2bf(float f) {
    unsigned u = __builtin_bit_cast(unsigned, f);
    unsigned r = u + 0x7fff + ((u >> 16) & 1);   // RNE
    return (unsigned short)(r >> 16);
}
__device__ __forceinline__ float lo_f(unsigned u) { return __builtin_bit_cast(float, u << 16); }
__device__ __forceinline__ float hi_f(unsigned u) { return __builtin_bit_cast(float, u & 0xffff0000u); }
__device__ __forceinline__ unsigned packbf(float lo, float hi) {
    return ((unsigned)f2bf(hi) << 16) | (unsigned)f2bf(lo);
}

// inline BatchNorm coefficient computation (channel = d in 0..63)
__device__ __forceinline__ void bn_coef(const float* __restrict__ ssum,
                                        const float* __restrict__ ssq,
                                        const float* __restrict__ g,
                                        const float* __restrict__ b, int j,
                                        float& sc, float& sh) {
    const float invM = 1.0f / (float)R_TOTAL;
    float m = ssum[j] * invM;
    float v = ssq[j] * invM - m * m;
    sc = g[j] * rsqrtf(v + 1e-5f);
    sh = b[j] - m * sc;
}

// ---------------- wprep: Wt[mat][col][k] = bf16(W[mat][k][col]), mat = {W0l0,W1l0,W0l1,W1l1} ----------------
__global__ __launch_bounds__(256) void k_wprep(const float* __restrict__ W0,
                                               const float* __restrict__ W1,
                                               ushort_t* __restrict__ wt) {
    int idx = blockIdx.x * 256 + threadIdx.x;      // 64 blocks -> 16384 = 4*4096
    int mm = idx >> 12, r = idx & 4095;
    int kk = r >> 6, col = r & 63;                 // read contiguous over col
    int l = mm >> 1;
    const float* src = ((mm & 1) ? W1 : W0) + l * 4096;
    wt[mm * 4096 + col * 64 + kk] = f2bf(src[kk * 64 + col]);
}

// ---------------- transpose h[a][d][c][n] -> xb[ac][n][d] (bf16, slice-major), + pooled0 ----------------
__global__ __launch_bounds__(256) void k_transpose(const float* __restrict__ h,
                                                   ushort_t* __restrict__ xb,
                                                   float* __restrict__ pooled) {
    __shared__ float tile[64][65];    // [d][nn]
    int tn = blockIdx.x;              // n-tile 0..156
    int ac = blockIdx.y;              // 0..29
    int a = ac / 15, c = ac % 15;
    int t = threadIdx.x;
    int n0 = tn * 64;

    int r = t >> 4, g = t & 15;
    int nbase = n0 + 4 * g;
    const float* hp = h + (size_t)a * 9600000 + (size_t)c * 10000;
#pragma unroll
    for (int it = 0; it < 4; it++) {
        int d = it * 16 + r;
        const float* p = hp + (size_t)d * 150000 + nbase;
        float4 v;
        if (nbase + 3 < N_NODES) {
            v = *(const float4*)p;
        } else {
            v.x = (nbase + 0 < N_NODES) ? p[0] : 0.f;
            v.y = (nbase + 1 < N_NODES) ? p[1] : 0.f;
            v.z = (nbase + 2 < N_NODES) ? p[2] : 0.f;
            v.w = (nbase + 3 < N_NODES) ? p[3] : 0.f;
        }
        tile[d][4 * g + 0] = v.x;
        tile[d][4 * g + 1] = v.y;
        tile[d][4 * g + 2] = v.z;
        tile[d][4 * g + 3] = v.w;
    }
    __syncthreads();

    int nn = t >> 2, dg = (t & 3) * 16;
    int n = n0 + nn;
    if (n < N_NODES) {
        u32x4 oA, oB;
#pragma unroll
        for (int q = 0; q < 4; q++) {
            oA[q] = packbf(tile[dg + 2 * q][nn],     tile[dg + 2 * q + 1][nn]);
            oB[q] = packbf(tile[dg + 8 + 2 * q][nn], tile[dg + 8 + 2 * q + 1][nn]);
        }
        ushort_t* dst = xb + ((size_t)ac * N_NODES + n) * 64 + dg;   // slice-major
        *(u32x4*)dst = oA;
        *(u32x4*)(dst + 8) = oB;
    }

    if (t < 64) {
        float s = 0.f;
        int lim = min(64, N_NODES - n0);
        for (int j = 0; j < lim; j++) s += tile[t][j];
        atomicAdd(&pooled[ac * 64 + t], s);
    }
}

// ---------------- CSR build: degree -> scan -> fill ----------------
__global__ void k_deg(const int* __restrict__ dst, int* __restrict__ deg) {
    int e = blockIdx.x * 256 + threadIdx.x;
    if (e < N_EDGES) atomicAdd(&deg[dst[e]], 1);
}

__global__ __launch_bounds__(256) void k_scan(const int* __restrict__ deg,
                                              int* __restrict__ off,
                                              int* __restrict__ cursor) {
    __shared__ int buf[256];
    int t = threadIdx.x;
    int c0 = t * 40;                 // 256*40 = 10240 >= 10000
    int local[40];
    int s = 0;
    for (int i = 0; i < 40; i++) {
        int idx = c0 + i;
        int d = (idx < N_NODES) ? deg[idx] : 0;
        local[i] = d;
        s += d;
    }
    buf[t] = s;
    __syncthreads();
    for (int st = 1; st < 256; st <<= 1) {
        int v = (t >= st) ? buf[t - st] : 0;
        __syncthreads();
        buf[t] += v;
        __syncthreads();
    }
    int run = buf[t] - s;
    for (int i = 0; i < 40; i++) {
        int idx = c0 + i;
        if (idx < N_NODES) {
            off[idx] = run;
            cursor[idx] = run;
            run += local[i];
        }
    }
    if (t == 255) off[N_NODES] = buf[255];
}

__global__ void k_fill(const int* __restrict__ src, const int* __restrict__ dst,
                       int* __restrict__ cursor, int* __restrict__ csr) {
    int e = blockIdx.x * 256 + threadIdx.x;
    if (e < N_EDGES) {
        int p = atomicAdd(&cursor[dst[e]], 1);
        csr[p] = src[e];
    }
}

// ---------------- gather (slice-major, XCD-partitioned), emits z = (1+eps)*x[n] + sum x[src] ----------------
__global__ __launch_bounds__(256) void k_gather(const ushort_t* __restrict__ xs,
                                                ushort_t* __restrict__ zs,
                                                const int* __restrict__ off,
                                                const int* __restrict__ csr,
                                                const float* __restrict__ epsp, int l) {
    int bid = blockIdx.x;
    int xcd = bid & 7, k = bid >> 3;
    int base = (xcd < 6) ? xcd * 4 : 24 + (xcd - 6) * 3;   // slices per XCD: 4,4,4,4,4,4,3,3
    int nsl  = (xcd < 6) ? 4 : 3;
    int si = k / BPS;
    if (si >= nsl) return;
    int ac = base + si;
    int ng = k - si * BPS;
    int t = threadIdx.x;
    int nl = t >> 3, c8 = t & 7;       // 32 nodes/block, 8 threads/node (16B chunk each)
    int n = ng * 32 + nl;
    if (n >= N_NODES) return;

    const ushort_t* xsl = xs + (size_t)ac * N_NODES * 64;
    float e1 = 1.0f + epsp[l];
    float acc[8];
    {
        u32x4 xv = *(const u32x4*)(xsl + (size_t)n * 64 + c8 * 8);
#pragma unroll
        for (int q = 0; q < 4; q++) {
            acc[2 * q]     = e1 * lo_f(xv[q]);
            acc[2 * q + 1] = e1 * hi_f(xv[q]);
        }
    }
    int e0 = off[n], e1i = off[n + 1];
    int i = e0;
    for (; i + 4 <= e1i; i += 4) {
        int s0 = csr[i], s1 = csr[i + 1], s2 = csr[i + 2], s3 = csr[i + 3];
        u32x4 v0 = *(const u32x4*)(xsl + (size_t)s0 * 64 + c8 * 8);
        u32x4 v1 = *(const u32x4*)(xsl + (size_t)s1 * 64 + c8 * 8);
        u32x4 v2 = *(const u32x4*)(xsl + (size_t)s2 * 64 + c8 * 8);
        u32x4 v3 = *(const u32x4*)(xsl + (size_t)s3 * 64 + c8 * 8);
#pragma unroll
        for (int q = 0; q < 4; q++) {
            acc[2 * q]     += (lo_f(v0[q]) + lo_f(v1[q])) + (lo_f(v2[q]) + lo_f(v3[q]));
            acc[2 * q + 1] += (hi_f(v0[q]) + hi_f(v1[q])) + (hi_f(v2[q]) + hi_f(v3[q]));
        }
    }
    for (; i < e1i; i++) {
        int s0 = csr[i];
        u32x4 v = *(const u32x4*)(xsl + (size_t)s0 * 64 + c8 * 8);
#pragma unroll
        for (int q = 0; q < 4; q++) {
            acc[2 * q]     += lo_f(v[q]);
            acc[2 * q + 1] += hi_f(v[q]);
        }
    }
    u32x4 o;
#pragma unroll
    for (int q = 0; q < 4; q++) o[q] = packbf(acc[2 * q], acc[2 * q + 1]);
    *(u32x4*)(zs + ((size_t)ac * N_NODES + n) * 64 + c8 * 8) = o;
}

// ---------------- passA (MFMA): to = z @ W0 + b0 ; stats(to). Pure-load A and W frags ----------------
__global__ __launch_bounds__(256) void k_passA(const ushort_t* __restrict__ zb,
                                               ushort_t* __restrict__ to,
                                               const ushort_t* __restrict__ wt,  // [col][k] bf16
                                               const float* __restrict__ bias,
                                               float* __restrict__ ssum, float* __restrict__ ssq) {
    int tid = threadIdx.x;
    int lane = tid & 63, wid = tid >> 6;
    int m = lane & 15, kg = lane >> 4;

    short8 bfr[2][4];                 // [kstep][nt] ; col = 4m+nt; pure 16B loads
#pragma unroll
    for (int s = 0; s < 2; s++)
#pragma unroll
        for (int nt = 0; nt < 4; nt++)
            bfr[s][nt] = *(const short8*)(wt + (4 * m + nt) * 64 + s * 32 + kg * 8);
    float bcol[4];
#pragma unroll
    for (int nt = 0; nt < 4; nt++) bcol[nt] = bias[4 * m + nt];

    float s0a[4] = {0.f, 0.f, 0.f, 0.f}, s1a[4] = {0.f, 0.f, 0.f, 0.f};

    for (int tile = blockIdx.x * 4 + wid; tile < N_TILES; tile += gridDim.x * 4) {
        size_t row0 = (size_t)tile * 16;
        const short8* zr = (const short8*)(zb + (row0 + m) * 64);
        short8 afr0 = zr[kg];          // k = kg*8 .. +7
        short8 afr1 = zr[4 + kg];      // k = 32 + kg*8 .. +7
        f32x4 acc0 = {0,0,0,0}, acc1 = {0,0,0,0}, acc2 = {0,0,0,0}, acc3 = {0,0,0,0};
        acc0 = __builtin_amdgcn_mfma_f32_16x16x32_bf16(afr0, bfr[0][0], acc0, 0, 0, 0);
        acc1 = __builtin_amdgcn_mfma_f32_16x16x32_bf16(afr0, bfr[0][1], acc1, 0, 0, 0);
        acc2 = __builtin_amdgcn_mfma_f32_16x16x32_bf16(afr0, bfr[0][2], acc2, 0, 0, 0);
        acc3 = __builtin_amdgcn_mfma_f32_16x16x32_bf16(afr0, bfr[0][3], acc3, 0, 0, 0);
        acc0 = __builtin_amdgcn_mfma_f32_16x16x32_bf16(afr1, bfr[1][0], acc0, 0, 0, 0);
        acc1 = __builtin_amdgcn_mfma_f32_16x16x32_bf16(afr1, bfr[1][1], acc1, 0, 0, 0);
        acc2 = __builtin_amdgcn_mfma_f32_16x16x32_bf16(afr1, bfr[1][2], acc2, 0, 0, 0);
        acc3 = __builtin_amdgcn_mfma_f32_16x16x32_bf16(afr1, bfr[1][3], acc3, 0, 0, 0);
        ushort_t* tw = to + (row0 + kg * 4) * 64 + 4 * m;
#pragma unroll
        for (int r = 0; r < 4; r++) {
            float v0 = acc0[r] + bcol[0];
            float v1 = acc1[r] + bcol[1];
            float v2 = acc2[r] + bcol[2];
            float v3 = acc3[r] + bcol[3];
            u32x2 pk;
            pk[0] = packbf(v0, v1);
            pk[1] = packbf(v2, v3);
            *(u32x2*)(tw + (size_t)r * 64) = pk;
            s0a[0] += v0; s1a[0] += v0 * v0;
            s0a[1] += v1; s1a[1] += v1 * v1;
            s0a[2] += v2; s1a[2] += v2 * v2;
            s0a[3] += v3; s1a[3] += v3 * v3;
        }
    }
    __shared__ float shs0[64], shs1[64];
    if (tid < 64) { shs0[tid] = 0.f; shs1[tid] = 0.f; }
    __syncthreads();
#pragma unroll
    for (int nt = 0; nt < 4; nt++) {
        atomicAdd(&shs0[4 * m + nt], s0a[nt]);
        atomicAdd(&shs1[4 * m + nt], s1a[nt]);
    }
    __syncthreads();
    if (tid < 64) {
        atomicAdd(&ssum[tid], shs0[tid]);
        atomicAdd(&ssq[tid], shs1[tid]);
    }
}

// ---------------- passB (MFMA): to = relu(bn0(ti)) @ W1 + b1 ; stats(to) ----------------
__global__ __launch_bounds__(256) void k_passB(const ushort_t* __restrict__ ti,
                                               ushort_t* __restrict__ to,
                                               const ushort_t* __restrict__ wt,  // [col][k] bf16
                                               const float* __restrict__ bias,
                                               const float* __restrict__ ssum0,
                                               const float* __restrict__ ssq0,
                                               const float* __restrict__ g0,
                                               const float* __restrict__ be0,
                                               float* __restrict__ ssum, float* __restrict__ ssq) {
    int tid = threadIdx.x;
    int lane = tid & 63, wid = tid >> 6;
    int m = lane & 15, kg = lane >> 4;

    short8 bfr[2][4];                 // col = 4m+nt; pure 16B loads
#pragma unroll
    for (int s = 0; s < 2; s++)
#pragma unroll
        for (int nt = 0; nt < 4; nt++)
            bfr[s][nt] = *(const short8*)(wt + (4 * m + nt) * 64 + s * 32 + kg * 8);
    float bcol[4];
#pragma unroll
    for (int nt = 0; nt < 4; nt++) bcol[nt] = bias[4 * m + nt];
    float scv[2][8], shv[2][8];       // BN for input channels k = s*32+kg*8+j
#pragma unroll
    for (int s = 0; s < 2; s++)
#pragma unroll
        for (int j = 0; j < 8; j++)
            bn_coef(ssum0, ssq0, g0, be0, s * 32 + kg * 8 + j, scv[s][j], shv[s][j]);

    float s0a[4] = {0.f, 0.f, 0.f, 0.f}, s1a[4] = {0.f, 0.f, 0.f, 0.f};

    for (int tile = blockIdx.x * 4 + wid; tile < N_TILES; tile += gridDim.x * 4) {
        size_t row0 = (size_t)tile * 16;
        const u32x4* tr = (const u32x4*)(ti + (row0 + m) * 64);
        short8 afr[2];
#pragma unroll
        for (int s = 0; s < 2; s++) {
            u32x4 tv = tr[s * 4 + kg];
            u32x4 zv;
#pragma unroll
            for (int q = 0; q < 4; q++) {
                float zl_ = fmaxf(fmaf(lo_f(tv[q]), scv[s][2 * q],     shv[s][2 * q]),     0.f);
                float zh_ = fmaxf(fmaf(hi_f(tv[q]), scv[s][2 * q + 1], shv[s][2 * q + 1]), 0.f);
                zv[q] = packbf(zl_, zh_);
            }
            afr[s] = __builtin_bit_cast(short8, zv);
        }
        f32x4 acc0 = {0,0,0,0}, acc1 = {0,0,0,0}, acc2 = {0,0,0,0}, acc3 = {0,0,0,0};
#pragma unroll
        for (int s = 0; s < 2; s++) {
            acc0 = __builtin_amdgcn_mfma_f32_16x16x32_bf16(afr[s], bfr[s][0], acc0, 0, 0, 0);
            acc1 = __builtin_amdgcn_mfma_f32_16x16x32_bf16(afr[s], bfr[s][1], acc1, 0, 0, 0);
            acc2 = __builtin_amdgcn_mfma_f32_16x16x32_bf16(afr[s], bfr[s][2], acc2, 0, 0, 0);
            acc3 = __builtin_amdgcn_mfma_f32_16x16x32_bf16(afr[s], bfr[s][3], acc3, 0, 0, 0);
        }
        ushort_t* tw = to + (row0 + kg * 4) * 64 + 4 * m;
#pragma unroll
        for (int r = 0; r < 4; r++) {
            float v0 = acc0[r] + bcol[0];
            float v1 = acc1[r] + bcol[1];
            float v2 = acc2[r] + bcol[2];
            float v3 = acc3[r] + bcol[3];
            u32x2 pk;
            pk[0] = packbf(v0, v1);
            pk[1] = packbf(v2, v3);
            *(u32x2*)(tw + (size_t)r * 64) = pk;
            s0a[0] += v0; s1a[0] += v0 * v0;
            s0a[1] += v1; s1a[1] += v1 * v1;
            s0a[2] += v2; s1a[2] += v2 * v2;
            s0a[3] += v3; s1a[3] += v3 * v3;
        }
    }
    __shared__ float shs0[64], shs1[64];
    if (tid < 64) { shs0[tid] = 0.f; shs1[tid] = 0.f; }
    __syncthreads();
#pragma unroll
    for (int nt = 0; nt < 4; nt++) {
        atomicAdd(&shs0[4 * m + nt], s0a[nt]);
        atomicAdd(&shs1[4 * m + nt], s1a[nt]);
    }
    __syncthreads();
    if (tid < 64) {
        atomicAdd(&ssum[tid], shs0[tid]);
        atomicAdd(&ssq[tid], shs1[tid]);
    }
}

// ---------------- statsC: stats of u = relu(bn_a(t3)), read-only bf16 ----------------
__global__ __launch_bounds__(256) void k_statsC(const ushort_t* __restrict__ tb,
                                                const float* __restrict__ ssum1,
                                                const float* __restrict__ ssq1,
                                                const float* __restrict__ ga,
                                                const float* __restrict__ ba,
                                                float* __restrict__ ssum2,
                                                float* __restrict__ ssq2) {
    __shared__ float shs0[64], shs1[64];
    int tid = threadIdx.x;
    if (tid < 64) { shs0[tid] = 0.f; shs1[tid] = 0.f; }
    __syncthreads();
    int ch0 = (tid & 7) * 8;          // chunk-in-row = tid%8 (stride is multiple of 8)
    float sc[8], sh[8];
#pragma unroll
    for (int j = 0; j < 8; j++) bn_coef(ssum1, ssq1, ga, ba, ch0 + j, sc[j], sh[j]);
    float s0[8] = {0,0,0,0,0,0,0,0}, s1[8] = {0,0,0,0,0,0,0,0};
    const u32x4* t4 = (const u32x4*)tb;
    const int total = ELEMS / 8;
    int stride = gridDim.x * 256;
    for (int i = blockIdx.x * 256 + tid; i < total; i += stride) {
        u32x4 v = t4[i];
#pragma unroll
        for (int q = 0; q < 4; q++) {
            float e;
            e = fmaxf(fmaf(lo_f(v[q]), sc[2 * q],     sh[2 * q]),     0.f);
            s0[2 * q] += e;     s1[2 * q] += e * e;
            e = fmaxf(fmaf(hi_f(v[q]), sc[2 * q + 1], sh[2 * q + 1]), 0.f);
            s0[2 * q + 1] += e; s1[2 * q + 1] += e * e;
        }
    }
#pragma unroll
    for (int j = 0; j < 8; j++) {
        atomicAdd(&shs0[ch0 + j], s0[j]);
        atomicAdd(&shs1[ch0 + j], s1[j]);
    }
    __syncthreads();
    if (tid < 64) {
        atomicAdd(&ssum2[tid], shs0[tid]);
        atomicAdd(&ssq2[tid], shs1[tid]);
    }
}

// ---------------- passD (slice-major): grid (PD_X, 30) ----------------
__global__ __launch_bounds__(256) void k_passD(const ushort_t* __restrict__ tb,
                                               ushort_t* __restrict__ xb,
                                               const float* __restrict__ ssum1,
                                               const float* __restrict__ ssq1,
                                               const float* __restrict__ ga,
                                               const float* __restrict__ ba,
                                               const float* __restrict__ ssum2,
                                               const float* __restrict__ ssq2,
                                               const float* __restrict__ go,
                                               const float* __restrict__ bo,
                                               float* __restrict__ pp,   // [30*PD_X][64]
                                               int writeX) {
    __shared__ float pl[64];
    int t = threadIdx.x;
    int nl = t >> 3, c8 = t & 7;
    int ac = blockIdx.y, bx = blockIdx.x;
    int ch0 = c8 * 8;                 // BN channel base (d only)
    float sc1[8], sh1[8], sc2[8], sh2[8];
#pragma unroll
    for (int j = 0; j < 8; j++) {
        bn_coef(ssum1, ssq1, ga, ba, ch0 + j, sc1[j], sh1[j]);
        bn_coef(ssum2, ssq2, go, bo, ch0 + j, sc2[j], sh2[j]);
    }
    if (t < 64) pl[t] = 0.f;
    __syncthreads();

    float pool[8] = {0,0,0,0,0,0,0,0};
    int n0 = bx * 250;
    for (int n = n0 + nl; n < n0 + 250; n += 32) {
        size_t r = (size_t)ac * N_NODES + n;
        u32x4 v = *(const u32x4*)(tb + r * 64 + ch0);
        u32x4 o;
#pragma unroll
        for (int q = 0; q < 4; q++) {
            float el = fmaxf(fmaf(fmaxf(fmaf(lo_f(v[q]), sc1[2 * q], sh1[2 * q]), 0.f),
                                  sc2[2 * q], sh2[2 * q]), 0.f);
            float eh = fmaxf(fmaf(fmaxf(fmaf(hi_f(v[q]), sc1[2 * q + 1], sh1[2 * q + 1]), 0.f),
                                  sc2[2 * q + 1], sh2[2 * q + 1]), 0.f);
            pool[2 * q] += el;
            pool[2 * q + 1] += eh;
            o[q] = packbf(el, eh);
        }
        if (writeX) *(u32x4*)(xb + r * 64 + ch0) = o;
    }
#pragma unroll
    for (int j = 0; j < 8; j++) atomicAdd(&pl[ch0 + j], pool[j]);
    __syncthreads();
    if (t < 64) pp[((size_t)ac * PD_X + bx) * 64 + t] = pl[t];
}

// ---------------- redpool: pooled[(z+1)][ch] = sum over PD_X partials; grid (8,1,2) ----------------
__global__ __launch_bounds__(256) void k_redpool(const float* __restrict__ pp0,
                                                 const float* __restrict__ pp1,
                                                 float* __restrict__ pooled) {
    int ch = blockIdx.x * 256 + threadIdx.x;
    if (ch >= NODE_F) return;
    const float* pp = (blockIdx.z == 0) ? pp0 : pp1;
    int ac = ch >> 6, d = ch & 63;
    float a = 0.f;
    for (int b = 0; b < PD_X; b++) a += pp[((size_t)ac * PD_X + b) * 64 + d];
    pooled[(blockIdx.z + 1) * NODE_F + ch] = a;
}

// ---------------- final readout: score + fc -> out[2] ----------------
__global__ void k_final(const float* __restrict__ pooled,   // [3][1920]
                        const float* __restrict__ Wp,       // [3][64][10]
                        const float* __restrict__ bp,       // [3][10]
                        const float* __restrict__ Wfc,      // [15][10]
                        const float* __restrict__ bfc, float* __restrict__ out) {
    __shared__ float oa[2];
    int t = threadIdx.x;
    if (t < 2) oa[t] = 0.f;
    __syncthreads();
    if (t < 300) {
        int a = t / 150, rem = t % 150, c = rem / 10, hh = rem % 10;
        int ac = a * 15 + c;
        float sc_sum = 0.f;
        for (int i = 0; i < 3; i++) {
            float s = bp[i * 10 + hh];
            const float* pp = pooled + i * NODE_F + ac * 64;
            const float* wp = Wp + i * 640 + hh;
            for (int d = 0; d < 64; d++) s += pp[d] * wp[d * 10];
            sc_sum += s;
        }
        atomicAdd(&oa[a], sc_sum * Wfc[c * 10 + hh]);
    }
    __syncthreads();
    if (t < 2) out[t] = oa[t] + bfc[0];
}

extern "C" void kernel_launch(void* const* d_in, const int* in_sizes, int n_in,
                              void* d_out, int out_size, void* d_ws, size_t ws_size,
                              hipStream_t stream) {
    const float* h   = (const float*)d_in[0];
    const float* eps = (const float*)d_in[1];
    const float* W0  = (const float*)d_in[2];
    const float* b0  = (const float*)d_in[3];
    const float* g0  = (const float*)d_in[4];
    const float* be0 = (const float*)d_in[5];
    const float* W1  = (const float*)d_in[6];
    const float* b1  = (const float*)d_in[7];
    const float* ga  = (const float*)d_in[8];
    const float* ba  = (const float*)d_in[9];
    const float* go  = (const float*)d_in[10];
    const float* bo  = (const float*)d_in[11];
    const float* Wp  = (const float*)d_in[12];
    const float* bp  = (const float*)d_in[13];
    const float* Wfc = (const float*)d_in[14];
    const float* bfc = (const float*)d_in[15];
    const int*   src = (const int*)d_in[16];
    const int*   dst = (const int*)d_in[17];
    float* out = (float*)d_out;

    ushort_t* xb   = (ushort_t*)d_ws;            // [ELEMS] bf16 (node features, slice-major)
    ushort_t* bufP = xb + ELEMS;                 // [ELEMS] bf16 (z / t3)
    ushort_t* bufQ = bufP + ELEMS;               // [ELEMS] bf16 (t1)
    float* small   = (float*)(bufQ + ELEMS);
    float* bn = small;                           // 6 x [sum64|sq64] padded to 256
    float* pooled = small + 6 * 256;             // [3][1920]
    int* ideg = (int*)(pooled + 3 * NODE_F);     // [10000]
    int* ioff = ideg + N_NODES;                  // [10001]
    int* icur = ioff + N_NODES + 1;              // [10000]
    int* icsr = icur + N_NODES;                  // [80000]
    float* pp0 = (float*)(icsr + N_EDGES);       // [30*PD_X][64] layer-1 pool partials
    float* pp1 = pp0 + 30 * PD_X * 64;           // [30*PD_X][64] layer-2 pool partials
    ushort_t* wt = (ushort_t*)(pp1 + 30 * PD_X * 64);   // [4][64][64] bf16 transposed weights

    hipMemsetAsync(small, 0,
                   (6 * 256 + 3 * NODE_F) * sizeof(float) + N_NODES * sizeof(int), stream);

    k_wprep<<<64, 256, 0, stream>>>(W0, W1, wt);
    k_deg<<<(N_EDGES + 255) / 256, 256, 0, stream>>>(dst, ideg);
    k_scan<<<1, 256, 0, stream>>>(ideg, ioff, icur);
    k_fill<<<(N_EDGES + 255) / 256, 256, 0, stream>>>(src, dst, icur, icsr);

    k_transpose<<<dim3(157, 30), 256, 0, stream>>>(h, xb, pooled);

    for (int l = 0; l < 2; l++) {
        float* s0s = bn + l * 3 * 256;
        float* s1s = s0s + 256;
        float* s2s = s1s + 256;
        float* ppl = (l == 0) ? pp0 : pp1;
        const ushort_t* wt0 = wt + (l * 2 + 0) * 4096;   // W0 of layer l
        const ushort_t* wt1 = wt + (l * 2 + 1) * 4096;   // W1 of layer l
        k_gather<<<8 * 4 * BPS, 256, 0, stream>>>(xb, bufP, ioff, icsr, eps, l);
        k_passA<<<GEMM_GRID, 256, 0, stream>>>(bufP, bufQ, wt0, b0 + l * 64,
                                               s0s, s0s + 64);
        k_passB<<<GEMM_GRID, 256, 0, stream>>>(bufQ, bufP, wt1, b1 + l * 64,
                                               s0s, s0s + 64, g0 + l * 64, be0 + l * 64,
                                               s1s, s1s + 64);
        k_statsC<<<1024, 256, 0, stream>>>(bufP, s1s, s1s + 64, ga + l * 64, ba + l * 64,
                                           s2s, s2s + 64);
        k_passD<<<dim3(PD_X, 30), 256, 0, stream>>>(bufP, xb, s1s, s1s + 64,
                                                    ga + l * 64, ba + l * 64,
                                                    s2s, s2s + 64, go + l * 64, bo + l * 64,
                                                    ppl, (l == 0) ? 1 : 0);
    }
    k_redpool<<<dim3(8, 1, 2), 256, 0, stream>>>(pp0, pp1, pooled);
    k_final<<<1, 320, 0, stream>>>(pooled, Wp, bp, Wfc, bfc, out);
}

// Round 21
// 420.420 us; speedup vs baseline: 1.2568x; 1.0284x over previous
//
#include <hip/hip_runtime.h>
#include <hip/hip_bf16.h>

// GIN forward: N=10000 nodes, E=80000 edges, per-node feature block [A=2][C=15][D=64]
// All inter-kernel tensors stored bf16; all reductions/BN/pool math in fp32.
// SLICE-MAJOR layout: row r = ac*10000 + n (ac=0..29). BN channel = idx%64 (unchanged).
// LESSONS LEDGER:
//  - R3/R11: do NOT fuse gather with GEMM (W-prologue can't amortize over 30 rows/node).
//  - R13/R15: cooperative BCD fusion refuted: grid.sync() ~65us each on 8-XCD MI355X.
//  - R16: slice-major gather (per-slice 1.28MB, XCD-partitioned) -> L2-resident. WIN.
//  - R17: 2-tile ILP unroll refuted (VGPR 60->88 dropped occupancy, offsetting MLP).
//  - R18: fold (1+eps)*x into gather -> passA single-stream pure-load A-frag. WIN (420us).
//  - R19: GEMM_GRID 2048 refuted (bn_coef prologue can't amortize at 2.3 tiles/wave).
//  - R20: pre-transposed W (wprep) neutral (W prologue wasn't binding); reverted.
#define N_NODES   10000
#define N_EDGES   80000
#define R_TOTAL   300000
#define ELEMS     19200000   // R_TOTAL*64
#define NODE_F    1920       // 30*64 elements per node
#define N_TILES   18750      // R_TOTAL/16
#define GEMM_GRID 1024       // passA/passB grid: 4.6 tiles/wave amortizes prologues
#define BPS       313        // gather blocks per slice (32 nodes/block)
#define PD_X      40         // passD blocks per slice (250 nodes each)

typedef __attribute__((ext_vector_type(8))) short short8;   // 8 bf16
typedef __attribute__((ext_vector_type(4))) float f32x4;
typedef __attribute__((ext_vector_type(4))) unsigned int u32x4;
typedef __attribute__((ext_vector_type(2))) unsigned int u32x2;
typedef unsigned short ushort_t;

__device__ __forceinline__ unsigned short f2bf(float f) {
    unsigned u = __builtin_bit_cast(unsigned, f);
    unsigned r = u + 0x7fff + ((u >> 16) & 1);   // RNE
    return (unsigned short)(r >> 16);
}
__device__ __forceinline__ float lo_f(unsigned u) { return __builtin_bit_cast(float, u << 16); }
__device__ __forceinline__ float hi_f(unsigned u) { return __builtin_bit_cast(float, u & 0xffff0000u); }
__device__ __forceinline__ unsigned packbf(float lo, float hi) {
    return ((unsigned)f2bf(hi) << 16) | (unsigned)f2bf(lo);
}

// inline BatchNorm coefficient computation (channel = d in 0..63)
__device__ __forceinline__ void bn_coef(const float* __restrict__ ssum,
                                        const float* __restrict__ ssq,
                                        const float* __restrict__ g,
                                        const float* __restrict__ b, int j,
                                        float& sc, float& sh) {
    const float invM = 1.0f / (float)R_TOTAL;
    float m = ssum[j] * invM;
    float v = ssq[j] * invM - m * m;
    sc = g[j] * rsqrtf(v + 1e-5f);
    sh = b[j] - m * sc;
}

// ---------------- transpose h[a][d][c][n] -> xb[ac][n][d] (bf16, slice-major), + pooled0 ----------------
__global__ __launch_bounds__(256) void k_transpose(const float* __restrict__ h,
                                                   ushort_t* __restrict__ xb,
                                                   float* __restrict__ pooled) {
    __shared__ float tile[64][65];    // [d][nn]
    int tn = blockIdx.x;              // n-tile 0..156
    int ac = blockIdx.y;              // 0..29
    int a = ac / 15, c = ac % 15;
    int t = threadIdx.x;
    int n0 = tn * 64;

    int r = t >> 4, g = t & 15;
    int nbase = n0 + 4 * g;
    const float* hp = h + (size_t)a * 9600000 + (size_t)c * 10000;
#pragma unroll
    for (int it = 0; it < 4; it++) {
        int d = it * 16 + r;
        const float* p = hp + (size_t)d * 150000 + nbase;
        float4 v;
        if (nbase + 3 < N_NODES) {
            v = *(const float4*)p;
        } else {
            v.x = (nbase + 0 < N_NODES) ? p[0] : 0.f;
            v.y = (nbase + 1 < N_NODES) ? p[1] : 0.f;
            v.z = (nbase + 2 < N_NODES) ? p[2] : 0.f;
            v.w = (nbase + 3 < N_NODES) ? p[3] : 0.f;
        }
        tile[d][4 * g + 0] = v.x;
        tile[d][4 * g + 1] = v.y;
        tile[d][4 * g + 2] = v.z;
        tile[d][4 * g + 3] = v.w;
    }
    __syncthreads();

    int nn = t >> 2, dg = (t & 3) * 16;
    int n = n0 + nn;
    if (n < N_NODES) {
        u32x4 oA, oB;
#pragma unroll
        for (int q = 0; q < 4; q++) {
            oA[q] = packbf(tile[dg + 2 * q][nn],     tile[dg + 2 * q + 1][nn]);
            oB[q] = packbf(tile[dg + 8 + 2 * q][nn], tile[dg + 8 + 2 * q + 1][nn]);
        }
        ushort_t* dst = xb + ((size_t)ac * N_NODES + n) * 64 + dg;   // slice-major
        *(u32x4*)dst = oA;
        *(u32x4*)(dst + 8) = oB;
    }

    if (t < 64) {
        float s = 0.f;
        int lim = min(64, N_NODES - n0);
        for (int j = 0; j < lim; j++) s += tile[t][j];
        atomicAdd(&pooled[ac * 64 + t], s);
    }
}

// ---------------- CSR build: degree -> scan -> fill ----------------
__global__ void k_deg(const int* __restrict__ dst, int* __restrict__ deg) {
    int e = blockIdx.x * 256 + threadIdx.x;
    if (e < N_EDGES) atomicAdd(&deg[dst[e]], 1);
}

__global__ __launch_bounds__(256) void k_scan(const int* __restrict__ deg,
                                              int* __restrict__ off,
                                              int* __restrict__ cursor) {
    __shared__ int buf[256];
    int t = threadIdx.x;
    int c0 = t * 40;                 // 256*40 = 10240 >= 10000
    int local[40];
    int s = 0;
    for (int i = 0; i < 40; i++) {
        int idx = c0 + i;
        int d = (idx < N_NODES) ? deg[idx] : 0;
        local[i] = d;
        s += d;
    }
    buf[t] = s;
    __syncthreads();
    for (int st = 1; st < 256; st <<= 1) {
        int v = (t >= st) ? buf[t - st] : 0;
        __syncthreads();
        buf[t] += v;
        __syncthreads();
    }
    int run = buf[t] - s;
    for (int i = 0; i < 40; i++) {
        int idx = c0 + i;
        if (idx < N_NODES) {
            off[idx] = run;
            cursor[idx] = run;
            run += local[i];
        }
    }
    if (t == 255) off[N_NODES] = buf[255];
}

__global__ void k_fill(const int* __restrict__ src, const int* __restrict__ dst,
                       int* __restrict__ cursor, int* __restrict__ csr) {
    int e = blockIdx.x * 256 + threadIdx.x;
    if (e < N_EDGES) {
        int p = atomicAdd(&cursor[dst[e]], 1);
        csr[p] = src[e];
    }
}

// ---------------- gather (slice-major, XCD-partitioned), emits z = (1+eps)*x[n] + sum x[src] ----------------
__global__ __launch_bounds__(256) void k_gather(const ushort_t* __restrict__ xs,
                                                ushort_t* __restrict__ zs,
                                                const int* __restrict__ off,
                                                const int* __restrict__ csr,
                                                const float* __restrict__ epsp, int l) {
    int bid = blockIdx.x;
    int xcd = bid & 7, k = bid >> 3;
    int base = (xcd < 6) ? xcd * 4 : 24 + (xcd - 6) * 3;   // slices per XCD: 4,4,4,4,4,4,3,3
    int nsl  = (xcd < 6) ? 4 : 3;
    int si = k / BPS;
    if (si >= nsl) return;
    int ac = base + si;
    int ng = k - si * BPS;
    int t = threadIdx.x;
    int nl = t >> 3, c8 = t & 7;       // 32 nodes/block, 8 threads/node (16B chunk each)
    int n = ng * 32 + nl;
    if (n >= N_NODES) return;

    const ushort_t* xsl = xs + (size_t)ac * N_NODES * 64;
    float e1 = 1.0f + epsp[l];
    float acc[8];
    {
        u32x4 xv = *(const u32x4*)(xsl + (size_t)n * 64 + c8 * 8);
#pragma unroll
        for (int q = 0; q < 4; q++) {
            acc[2 * q]     = e1 * lo_f(xv[q]);
            acc[2 * q + 1] = e1 * hi_f(xv[q]);
        }
    }
    int e0 = off[n], e1i = off[n + 1];
    int i = e0;
    for (; i + 4 <= e1i; i += 4) {
        int s0 = csr[i], s1 = csr[i + 1], s2 = csr[i + 2], s3 = csr[i + 3];
        u32x4 v0 = *(const u32x4*)(xsl + (size_t)s0 * 64 + c8 * 8);
        u32x4 v1 = *(const u32x4*)(xsl + (size_t)s1 * 64 + c8 * 8);
        u32x4 v2 = *(const u32x4*)(xsl + (size_t)s2 * 64 + c8 * 8);
        u32x4 v3 = *(const u32x4*)(xsl + (size_t)s3 * 64 + c8 * 8);
#pragma unroll
        for (int q = 0; q < 4; q++) {
            acc[2 * q]     += (lo_f(v0[q]) + lo_f(v1[q])) + (lo_f(v2[q]) + lo_f(v3[q]));
            acc[2 * q + 1] += (hi_f(v0[q]) + hi_f(v1[q])) + (hi_f(v2[q]) + hi_f(v3[q]));
        }
    }
    for (; i < e1i; i++) {
        int s0 = csr[i];
        u32x4 v = *(const u32x4*)(xsl + (size_t)s0 * 64 + c8 * 8);
#pragma unroll
        for (int q = 0; q < 4; q++) {
            acc[2 * q]     += lo_f(v[q]);
            acc[2 * q + 1] += hi_f(v[q]);
        }
    }
    u32x4 o;
#pragma unroll
    for (int q = 0; q < 4; q++) o[q] = packbf(acc[2 * q], acc[2 * q + 1]);
    *(u32x4*)(zs + ((size_t)ac * N_NODES + n) * 64 + c8 * 8) = o;
}

// ---------------- passA (MFMA): to = z @ W0 + b0 ; stats(to). z pre-built by gather ----------------
// A-frag is a PURE LOAD (z already bf16): 2x16B per lane, no VALU prep.
__global__ __launch_bounds__(256) void k_passA(const ushort_t* __restrict__ zb,
                                               ushort_t* __restrict__ to,
                                               const float* __restrict__ W,
                                               const float* __restrict__ bias,
                                               float* __restrict__ ssum, float* __restrict__ ssq) {
    int tid = threadIdx.x;
    int lane = tid & 63, wid = tid >> 6;
    int m = lane & 15, kg = lane >> 4;

    short8 bfr[2][4];                 // [kstep][nt] ; col = 4m+nt
#pragma unroll
    for (int s = 0; s < 2; s++)
#pragma unroll
        for (int nt = 0; nt < 4; nt++) {
            short8 v;
#pragma unroll
            for (int j = 0; j < 8; j++)
                v[j] = (short)f2bf(W[(s * 32 + kg * 8 + j) * 64 + 4 * m + nt]);
            bfr[s][nt] = v;
        }
    float bcol[4];
#pragma unroll
    for (int nt = 0; nt < 4; nt++) bcol[nt] = bias[4 * m + nt];

    float s0a[4] = {0.f, 0.f, 0.f, 0.f}, s1a[4] = {0.f, 0.f, 0.f, 0.f};

    for (int tile = blockIdx.x * 4 + wid; tile < N_TILES; tile += gridDim.x * 4) {
        size_t row0 = (size_t)tile * 16;
        const short8* zr = (const short8*)(zb + (row0 + m) * 64);
        short8 afr0 = zr[kg];          // k = kg*8 .. +7   (layout: [row][64] bf16, 8 chunks of 8)
        short8 afr1 = zr[4 + kg];      // k = 32 + kg*8 .. +7
        f32x4 acc0 = {0,0,0,0}, acc1 = {0,0,0,0}, acc2 = {0,0,0,0}, acc3 = {0,0,0,0};
        acc0 = __builtin_amdgcn_mfma_f32_16x16x32_bf16(afr0, bfr[0][0], acc0, 0, 0, 0);
        acc1 = __builtin_amdgcn_mfma_f32_16x16x32_bf16(afr0, bfr[0][1], acc1, 0, 0, 0);
        acc2 = __builtin_amdgcn_mfma_f32_16x16x32_bf16(afr0, bfr[0][2], acc2, 0, 0, 0);
        acc3 = __builtin_amdgcn_mfma_f32_16x16x32_bf16(afr0, bfr[0][3], acc3, 0, 0, 0);
        acc0 = __builtin_amdgcn_mfma_f32_16x16x32_bf16(afr1, bfr[1][0], acc0, 0, 0, 0);
        acc1 = __builtin_amdgcn_mfma_f32_16x16x32_bf16(afr1, bfr[1][1], acc1, 0, 0, 0);
        acc2 = __builtin_amdgcn_mfma_f32_16x16x32_bf16(afr1, bfr[1][2], acc2, 0, 0, 0);
        acc3 = __builtin_amdgcn_mfma_f32_16x16x32_bf16(afr1, bfr[1][3], acc3, 0, 0, 0);
        ushort_t* tw = to + (row0 + kg * 4) * 64 + 4 * m;
#pragma unroll
        for (int r = 0; r < 4; r++) {
            float v0 = acc0[r] + bcol[0];
            float v1 = acc1[r] + bcol[1];
            float v2 = acc2[r] + bcol[2];
            float v3 = acc3[r] + bcol[3];
            u32x2 pk;
            pk[0] = packbf(v0, v1);
            pk[1] = packbf(v2, v3);
            *(u32x2*)(tw + (size_t)r * 64) = pk;
            s0a[0] += v0; s1a[0] += v0 * v0;
            s0a[1] += v1; s1a[1] += v1 * v1;
            s0a[2] += v2; s1a[2] += v2 * v2;
            s0a[3] += v3; s1a[3] += v3 * v3;
        }
    }
    __shared__ float shs0[64], shs1[64];
    if (tid < 64) { shs0[tid] = 0.f; shs1[tid] = 0.f; }
    __syncthreads();
#pragma unroll
    for (int nt = 0; nt < 4; nt++) {
        atomicAdd(&shs0[4 * m + nt], s0a[nt]);
        atomicAdd(&shs1[4 * m + nt], s1a[nt]);
    }
    __syncthreads();
    if (tid < 64) {
        atomicAdd(&ssum[tid], shs0[tid]);
        atomicAdd(&ssq[tid], shs1[tid]);
    }
}

// ---------------- passB (MFMA): to = relu(bn0(ti)) @ W1 + b1 ; stats(to) ----------------
__global__ __launch_bounds__(256) void k_passB(const ushort_t* __restrict__ ti,
                                               ushort_t* __restrict__ to,
                                               const float* __restrict__ W,
                                               const float* __restrict__ bias,
                                               const float* __restrict__ ssum0,
                                               const float* __restrict__ ssq0,
                                               const float* __restrict__ g0,
                                               const float* __restrict__ be0,
                                               float* __restrict__ ssum, float* __restrict__ ssq) {
    int tid = threadIdx.x;
    int lane = tid & 63, wid = tid >> 6;
    int m = lane & 15, kg = lane >> 4;

    short8 bfr[2][4];                 // col = 4m+nt
#pragma unroll
    for (int s = 0; s < 2; s++)
#pragma unroll
        for (int nt = 0; nt < 4; nt++) {
            short8 v;
#pragma unroll
            for (int j = 0; j < 8; j++)
                v[j] = (short)f2bf(W[(s * 32 + kg * 8 + j) * 64 + 4 * m + nt]);
            bfr[s][nt] = v;
        }
    float bcol[4];
#pragma unroll
    for (int nt = 0; nt < 4; nt++) bcol[nt] = bias[4 * m + nt];
    float scv[2][8], shv[2][8];       // BN for input channels k = s*32+kg*8+j
#pragma unroll
    for (int s = 0; s < 2; s++)
#pragma unroll
        for (int j = 0; j < 8; j++)
            bn_coef(ssum0, ssq0, g0, be0, s * 32 + kg * 8 + j, scv[s][j], shv[s][j]);

    float s0a[4] = {0.f, 0.f, 0.f, 0.f}, s1a[4] = {0.f, 0.f, 0.f, 0.f};

    for (int tile = blockIdx.x * 4 + wid; tile < N_TILES; tile += gridDim.x * 4) {
        size_t row0 = (size_t)tile * 16;
        const u32x4* tr = (const u32x4*)(ti + (row0 + m) * 64);
        short8 afr[2];
#pragma unroll
        for (int s = 0; s < 2; s++) {
            u32x4 tv = tr[s * 4 + kg];
            u32x4 zv;
#pragma unroll
            for (int q = 0; q < 4; q++) {
                float zl_ = fmaxf(fmaf(lo_f(tv[q]), scv[s][2 * q],     shv[s][2 * q]),     0.f);
                float zh_ = fmaxf(fmaf(hi_f(tv[q]), scv[s][2 * q + 1], shv[s][2 * q + 1]), 0.f);
                zv[q] = packbf(zl_, zh_);
            }
            afr[s] = __builtin_bit_cast(short8, zv);
        }
        f32x4 acc0 = {0,0,0,0}, acc1 = {0,0,0,0}, acc2 = {0,0,0,0}, acc3 = {0,0,0,0};
#pragma unroll
        for (int s = 0; s < 2; s++) {
            acc0 = __builtin_amdgcn_mfma_f32_16x16x32_bf16(afr[s], bfr[s][0], acc0, 0, 0, 0);
            acc1 = __builtin_amdgcn_mfma_f32_16x16x32_bf16(afr[s], bfr[s][1], acc1, 0, 0, 0);
            acc2 = __builtin_amdgcn_mfma_f32_16x16x32_bf16(afr[s], bfr[s][2], acc2, 0, 0, 0);
            acc3 = __builtin_amdgcn_mfma_f32_16x16x32_bf16(afr[s], bfr[s][3], acc3, 0, 0, 0);
        }
        ushort_t* tw = to + (row0 + kg * 4) * 64 + 4 * m;
#pragma unroll
        for (int r = 0; r < 4; r++) {
            float v0 = acc0[r] + bcol[0];
            float v1 = acc1[r] + bcol[1];
            float v2 = acc2[r] + bcol[2];
            float v3 = acc3[r] + bcol[3];
            u32x2 pk;
            pk[0] = packbf(v0, v1);
            pk[1] = packbf(v2, v3);
            *(u32x2*)(tw + (size_t)r * 64) = pk;
            s0a[0] += v0; s1a[0] += v0 * v0;
            s0a[1] += v1; s1a[1] += v1 * v1;
            s0a[2] += v2; s1a[2] += v2 * v2;
            s0a[3] += v3; s1a[3] += v3 * v3;
        }
    }
    __shared__ float shs0[64], shs1[64];
    if (tid < 64) { shs0[tid] = 0.f; shs1[tid] = 0.f; }
    __syncthreads();
#pragma unroll
    for (int nt = 0; nt < 4; nt++) {
        atomicAdd(&shs0[4 * m + nt], s0a[nt]);
        atomicAdd(&shs1[4 * m + nt], s1a[nt]);
    }
    __syncthreads();
    if (tid < 64) {
        atomicAdd(&ssum[tid], shs0[tid]);
        atomicAdd(&ssq[tid], shs1[tid]);
    }
}

// ---------------- statsC: stats of u = relu(bn_a(t3)), read-only bf16 ----------------
__global__ __launch_bounds__(256) void k_statsC(const ushort_t* __restrict__ tb,
                                                const float* __restrict__ ssum1,
                                                const float* __restrict__ ssq1,
                                                const float* __restrict__ ga,
                                                const float* __restrict__ ba,
                                                float* __restrict__ ssum2,
                                                float* __restrict__ ssq2) {
    __shared__ float shs0[64], shs1[64];
    int tid = threadIdx.x;
    if (tid < 64) { shs0[tid] = 0.f; shs1[tid] = 0.f; }
    __syncthreads();
    int ch0 = (tid & 7) * 8;          // chunk-in-row = tid%8 (stride is multiple of 8)
    float sc[8], sh[8];
#pragma unroll
    for (int j = 0; j < 8; j++) bn_coef(ssum1, ssq1, ga, ba, ch0 + j, sc[j], sh[j]);
    float s0[8] = {0,0,0,0,0,0,0,0}, s1[8] = {0,0,0,0,0,0,0,0};
    const u32x4* t4 = (const u32x4*)tb;
    const int total = ELEMS / 8;
    int stride = gridDim.x * 256;
    for (int i = blockIdx.x * 256 + tid; i < total; i += stride) {
        u32x4 v = t4[i];
#pragma unroll
        for (int q = 0; q < 4; q++) {
            float e;
            e = fmaxf(fmaf(lo_f(v[q]), sc[2 * q],     sh[2 * q]),     0.f);
            s0[2 * q] += e;     s1[2 * q] += e * e;
            e = fmaxf(fmaf(hi_f(v[q]), sc[2 * q + 1], sh[2 * q + 1]), 0.f);
            s0[2 * q + 1] += e; s1[2 * q + 1] += e * e;
        }
    }
#pragma unroll
    for (int j = 0; j < 8; j++) {
        atomicAdd(&shs0[ch0 + j], s0[j]);
        atomicAdd(&shs1[ch0 + j], s1[j]);
    }
    __syncthreads();
    if (tid < 64) {
        atomicAdd(&ssum2[tid], shs0[tid]);
        atomicAdd(&ssq2[tid], shs1[tid]);
    }
}

// ---------------- passD (slice-major): grid (PD_X, 30) ----------------
__global__ __launch_bounds__(256) void k_passD(const ushort_t* __restrict__ tb,
                                               ushort_t* __restrict__ xb,
                                               const float* __restrict__ ssum1,
                                               const float* __restrict__ ssq1,
                                               const float* __restrict__ ga,
                                               const float* __restrict__ ba,
                                               const float* __restrict__ ssum2,
                                               const float* __restrict__ ssq2,
                                               const float* __restrict__ go,
                                               const float* __restrict__ bo,
                                               float* __restrict__ pp,   // [30*PD_X][64]
                                               int writeX) {
    __shared__ float pl[64];
    int t = threadIdx.x;
    int nl = t >> 3, c8 = t & 7;
    int ac = blockIdx.y, bx = blockIdx.x;
    int ch0 = c8 * 8;                 // BN channel base (d only)
    float sc1[8], sh1[8], sc2[8], sh2[8];
#pragma unroll
    for (int j = 0; j < 8; j++) {
        bn_coef(ssum1, ssq1, ga, ba, ch0 + j, sc1[j], sh1[j]);
        bn_coef(ssum2, ssq2, go, bo, ch0 + j, sc2[j], sh2[j]);
    }
    if (t < 64) pl[t] = 0.f;
    __syncthreads();

    float pool[8] = {0,0,0,0,0,0,0,0};
    int n0 = bx * 250;
    for (int n = n0 + nl; n < n0 + 250; n += 32) {
        size_t r = (size_t)ac * N_NODES + n;
        u32x4 v = *(const u32x4*)(tb + r * 64 + ch0);
        u32x4 o;
#pragma unroll
        for (int q = 0; q < 4; q++) {
            float el = fmaxf(fmaf(fmaxf(fmaf(lo_f(v[q]), sc1[2 * q], sh1[2 * q]), 0.f),
                                  sc2[2 * q], sh2[2 * q]), 0.f);
            float eh = fmaxf(fmaf(fmaxf(fmaf(hi_f(v[q]), sc1[2 * q + 1], sh1[2 * q + 1]), 0.f),
                                  sc2[2 * q + 1], sh2[2 * q + 1]), 0.f);
            pool[2 * q] += el;
            pool[2 * q + 1] += eh;
            o[q] = packbf(el, eh);
        }
        if (writeX) *(u32x4*)(xb + r * 64 + ch0) = o;
    }
#pragma unroll
    for (int j = 0; j < 8; j++) atomicAdd(&pl[ch0 + j], pool[j]);
    __syncthreads();
    if (t < 64) pp[((size_t)ac * PD_X + bx) * 64 + t] = pl[t];
}

// ---------------- redpool: pooled[(z+1)][ch] = sum over PD_X partials; grid (8,1,2) ----------------
__global__ __launch_bounds__(256) void k_redpool(const float* __restrict__ pp0,
                                                 const float* __restrict__ pp1,
                                                 float* __restrict__ pooled) {
    int ch = blockIdx.x * 256 + threadIdx.x;
    if (ch >= NODE_F) return;
    const float* pp = (blockIdx.z == 0) ? pp0 : pp1;
    int ac = ch >> 6, d = ch & 63;
    float a = 0.f;
    for (int b = 0; b < PD_X; b++) a += pp[((size_t)ac * PD_X + b) * 64 + d];
    pooled[(blockIdx.z + 1) * NODE_F + ch] = a;
}

// ---------------- final readout: score + fc -> out[2] ----------------
__global__ void k_final(const float* __restrict__ pooled,   // [3][1920]
                        const float* __restrict__ Wp,       // [3][64][10]
                        const float* __restrict__ bp,       // [3][10]
                        const float* __restrict__ Wfc,      // [15][10]
                        const float* __restrict__ bfc, float* __restrict__ out) {
    __shared__ float oa[2];
    int t = threadIdx.x;
    if (t < 2) oa[t] = 0.f;
    __syncthreads();
    if (t < 300) {
        int a = t / 150, rem = t % 150, c = rem / 10, hh = rem % 10;
        int ac = a * 15 + c;
        float sc_sum = 0.f;
        for (int i = 0; i < 3; i++) {
            float s = bp[i * 10 + hh];
            const float* pp = pooled + i * NODE_F + ac * 64;
            const float* wp = Wp + i * 640 + hh;
            for (int d = 0; d < 64; d++) s += pp[d] * wp[d * 10];
            sc_sum += s;
        }
        atomicAdd(&oa[a], sc_sum * Wfc[c * 10 + hh]);
    }
    __syncthreads();
    if (t < 2) out[t] = oa[t] + bfc[0];
}

extern "C" void kernel_launch(void* const* d_in, const int* in_sizes, int n_in,
                              void* d_out, int out_size, void* d_ws, size_t ws_size,
                              hipStream_t stream) {
    const float* h   = (const float*)d_in[0];
    const float* eps = (const float*)d_in[1];
    const float* W0  = (const float*)d_in[2];
    const float* b0  = (const float*)d_in[3];
    const float* g0  = (const float*)d_in[4];
    const float* be0 = (const float*)d_in[5];
    const float* W1  = (const float*)d_in[6];
    const float* b1  = (const float*)d_in[7];
    const float* ga  = (const float*)d_in[8];
    const float* ba  = (const float*)d_in[9];
    const float* go  = (const float*)d_in[10];
    const float* bo  = (const float*)d_in[11];
    const float* Wp  = (const float*)d_in[12];
    const float* bp  = (const float*)d_in[13];
    const float* Wfc = (const float*)d_in[14];
    const float* bfc = (const float*)d_in[15];
    const int*   src = (const int*)d_in[16];
    const int*   dst = (const int*)d_in[17];
    float* out = (float*)d_out;

    ushort_t* xb   = (ushort_t*)d_ws;            // [ELEMS] bf16 (node features, slice-major)
    ushort_t* bufP = xb + ELEMS;                 // [ELEMS] bf16 (z / t3)
    ushort_t* bufQ = bufP + ELEMS;               // [ELEMS] bf16 (t1)
    float* small   = (float*)(bufQ + ELEMS);
    float* bn = small;                           // 6 x [sum64|sq64] padded to 256
    float* pooled = small + 6 * 256;             // [3][1920]
    int* ideg = (int*)(pooled + 3 * NODE_F);     // [10000]
    int* ioff = ideg + N_NODES;                  // [10001]
    int* icur = ioff + N_NODES + 1;              // [10000]
    int* icsr = icur + N_NODES;                  // [80000]
    float* pp0 = (float*)(icsr + N_EDGES);       // [30*PD_X][64] layer-1 pool partials
    float* pp1 = pp0 + 30 * PD_X * 64;           // [30*PD_X][64] layer-2 pool partials

    hipMemsetAsync(small, 0,
                   (6 * 256 + 3 * NODE_F) * sizeof(float) + N_NODES * sizeof(int), stream);

    k_deg<<<(N_EDGES + 255) / 256, 256, 0, stream>>>(dst, ideg);
    k_scan<<<1, 256, 0, stream>>>(ideg, ioff, icur);
    k_fill<<<(N_EDGES + 255) / 256, 256, 0, stream>>>(src, dst, icur, icsr);

    k_transpose<<<dim3(157, 30), 256, 0, stream>>>(h, xb, pooled);

    for (int l = 0; l < 2; l++) {
        float* s0s = bn + l * 3 * 256;
        float* s1s = s0s + 256;
        float* s2s = s1s + 256;
        float* ppl = (l == 0) ? pp0 : pp1;
        // gather emits z = (1+eps)*x + sum(neigh) directly -> bufP
        k_gather<<<8 * 4 * BPS, 256, 0, stream>>>(xb, bufP, ioff, icsr, eps, l);
        k_passA<<<GEMM_GRID, 256, 0, stream>>>(bufP, bufQ, W0 + l * 4096, b0 + l * 64,
                                               s0s, s0s + 64);
        k_passB<<<GEMM_GRID, 256, 0, stream>>>(bufQ, bufP, W1 + l * 4096, b1 + l * 64,
                                               s0s, s0s + 64, g0 + l * 64, be0 + l * 64,
                                               s1s, s1s + 64);
        k_statsC<<<1024, 256, 0, stream>>>(bufP, s1s, s1s + 64, ga + l * 64, ba + l * 64,
                                           s2s, s2s + 64);
        k_passD<<<dim3(PD_X, 30), 256, 0, stream>>>(bufP, xb, s1s, s1s + 64,
                                                    ga + l * 64, ba + l * 64,
                                                    s2s, s2s + 64, go + l * 64, bo + l * 64,
                                                    ppl, (l == 0) ? 1 : 0);
    }
    k_redpool<<<dim3(8, 1, 2), 256, 0, stream>>>(pp0, pp1, pooled);
    k_final<<<1, 320, 0, stream>>>(pooled, Wp, bp, Wfc, bfc, out);
}